// Round 6
// baseline (820.652 us; speedup 1.0000x reference)
//
#include <hip/hip_runtime.h>
#include <hip/hip_bf16.h>

#define Bn   4096
#define Sn   128
#define En   768
#define HIDn 384
#define NHn  9
#define NEn  5
#define MAXTILES 41
#define NBLK 768

// flags layout (ints): 0 packdone, 1 poolall, 2..33 pooltile[32],
// 34 prep ticket, 35 pool ticket, 36 gemm ticket
#define F_PACKDONE 0
#define F_POOLALL  1
#define F_TILE     2
#define F_TPREP    34
#define F_TPOOL    35
#define F_TGEMM    36

typedef __attribute__((ext_vector_type(8))) short short8;
typedef __attribute__((ext_vector_type(4))) float f32x4;

__device__ __forceinline__ unsigned short f2bf(float v) {
  unsigned int x = __float_as_uint(v);
  x += 0x7fffu + ((x >> 16) & 1u);   // RNE
  return (unsigned short)(x >> 16);
}
__device__ __forceinline__ float dot4(float4 a, float4 b) {
  return fmaf(a.x, b.x, fmaf(a.y, b.y, fmaf(a.z, b.z, a.w * b.w)));
}
__device__ __forceinline__ void fma4(float4& p, float w, float4 v) {
  p.x = fmaf(w, v.x, p.x); p.y = fmaf(w, v.y, p.y);
  p.z = fmaf(w, v.z, p.z); p.w = fmaf(w, v.w, p.w);
}
__device__ __forceinline__ int aload(int* p) {
  return __hip_atomic_load(p, __ATOMIC_ACQUIRE, __HIP_MEMORY_SCOPE_AGENT);
}
__device__ __forceinline__ int aadd(int* p, int v) {
  return __hip_atomic_fetch_add(p, v, __ATOMIC_RELEASE, __HIP_MEMORY_SCOPE_AGENT);
}

union SM {
  struct { float pbuf[4][768]; float sbuf[4]; } pool;
  struct { int hist[NHn][256]; int padbase[NHn]; int total[NHn];
           int tilecat[MAXTILES]; int padTiles; } srt;
  struct { unsigned short Alds[128 * 40]; unsigned short Blds[8 * 512];
           union { struct { float hwlds[NHn * HIDn]; float plds[2][128]; } e;
                   struct { int rs[128]; float w2lds[640]; } g; } u; } gemm;
};

__global__ void zero_kernel(int* __restrict__ flags) { flags[threadIdx.x] = 0; }

__global__ __launch_bounds__(256, 2) void mega_kernel(
    const float* __restrict__ feature, const int* __restrict__ masks,
    const float* __restrict__ attn_w, const float* __restrict__ ew,
    const float* __restrict__ g1, const int* __restrict__ category,
    const float* __restrict__ gb1, const float* __restrict__ g2,
    const float* __restrict__ eb, const float* __restrict__ hw,
    unsigned short* __restrict__ pooled, unsigned short* __restrict__ Bpe,
    unsigned short* __restrict__ Bpg, int* __restrict__ rowsamp,
    int* __restrict__ meta, float* __restrict__ partial,
    float* __restrict__ glogp, int* __restrict__ flags) {
  __shared__ SM sm;
  __shared__ int curu;
  const int t = threadIdx.x, lane = t & 63, wid = t >> 6;

  // ================= phase 1: pack (units 0..2015) + sort (2016) ===========
  int nmine = 0;
  for (;;) {
    __syncthreads();
    if (t == 0) curu = __hip_atomic_fetch_add(&flags[F_TPREP], 1, __ATOMIC_RELAXED, __HIP_MEMORY_SCOPE_AGENT);
    __syncthreads();
    const int u = curu;
    if (u >= 2017) break;
    ++nmine;
    if (u < 2016) {                        // ---- pack: 4 frag-tiles ----
      const int pair = u * 4 + wid;
      const int q = lane >> 4, j = lane & 15;
      const float* src; unsigned short* dst; int kt;
      if (pair < 2880) {                   // expert: 120 ntiles x 24 kt
        int nt = pair / 24; kt = pair % 24;
        int col = nt * 16 + j;
        src = ew + (size_t)(col / HIDn) * (En * HIDn) + (col % HIDn);
        dst = Bpe + (size_t)pair * 512;
      } else {                             // gate: 9 heads x 24 ntiles x 24 kt
        int g = pair - 2880;
        int h = g / 576, rem = g % 576;
        int nt = rem / 24; kt = rem % 24;
        int col = nt * 16 + j;
        src = g1 + (size_t)h * (En * HIDn) + col;
        dst = Bpg + ((size_t)(h * 24 + nt) * 24 + kt) * 512;
      }
      unsigned short outv[8] __attribute__((aligned(16)));
      #pragma unroll
      for (int e = 0; e < 8; ++e) {
        int k = kt * 32 + q * 8 + e;
        outv[e] = f2bf(src[(size_t)k * HIDn]);
      }
      *(uint4*)&dst[lane * 8] = *(const uint4*)outv;
    } else {                               // ---- sort ----
      #pragma unroll
      for (int jj = 0; jj < NHn; ++jj) sm.srt.hist[jj][t] = 0;
      __syncthreads();
      for (int i = 0; i < 16; ++i) { int c = category[t * 16 + i]; sm.srt.hist[c][t]++; }
      __syncthreads();
      if (t < NHn) {
        int run = 0;
        for (int x = 0; x < 256; ++x) { int v = sm.srt.hist[t][x]; sm.srt.hist[t][x] = run; run += v; }
        sm.srt.total[t] = run;
      }
      __syncthreads();
      if (t == 0) {
        int pb = 0, mt = 0;
        for (int jj = 0; jj < NHn; ++jj) {
          sm.srt.padbase[jj] = pb;
          int tot = sm.srt.total[jj];
          int nt = (tot + 127) >> 7;
          for (int k2 = 0; k2 < nt; ++k2) {
            meta[1 + mt + k2] = jj;
            int vv = tot - (k2 << 7); if (vv > 128) vv = 128;
            meta[64 + mt + k2] = vv;
            sm.srt.tilecat[mt + k2] = jj;
          }
          mt += nt; pb += nt << 7;
        }
        meta[0] = mt; sm.srt.padTiles = mt;
      }
      __syncthreads();
      const int padM = sm.srt.padTiles << 7;
      for (int mm = t; mm < padM; mm += 256) {
        int h = sm.srt.tilecat[mm >> 7];
        if (mm - sm.srt.padbase[h] >= sm.srt.total[h]) rowsamp[mm] = 0;
      }
      for (int i = 0; i < 16; ++i) {       // stable scatter
        int idx = t * 16 + i; int c = category[idx];
        int off = sm.srt.hist[c][t]++;
        rowsamp[sm.srt.padbase[c] + off] = idx;
      }
    }
  }
  __syncthreads();
  if (t == 0) { __threadfence(); aadd(&flags[F_PACKDONE], nmine); }

  // ================= phase 2: pool (one unit = one sample) =================
  for (;;) {
    __syncthreads();
    if (t == 0) curu = __hip_atomic_fetch_add(&flags[F_TPOOL], 1, __ATOMIC_RELAXED, __HIP_MEMORY_SCOPE_AGENT);
    __syncthreads();
    const int b = curu;
    if (b >= Bn) break;
    const float4* aw = (const float4*)attn_w;
    const float4 aw0 = aw[lane], aw1 = aw[64 + lane], aw2 = aw[128 + lane];
    const float4* fb = (const float4*)(feature + (size_t)b * (Sn * En));
    unsigned long long bal = __ballot(lane < 32 && masks[b * Sn + wid * 32 + (lane & 31)] != 0);
    unsigned int m = (unsigned int)bal;
    float4 p0 = {0,0,0,0}, p1 = {0,0,0,0}, p2 = {0,0,0,0};
    float lsum = 0.f;
    if (m) {
      int s = __builtin_ctz(m); m &= m - 1;
      const float4* rp = fb + (wid * 32 + s) * (En / 4);
      float4 c0 = rp[lane], c1 = rp[64 + lane], c2 = rp[128 + lane];
      while (m) {
        int s2 = __builtin_ctz(m); m &= m - 1;
        const float4* rp2 = fb + (wid * 32 + s2) * (En / 4);
        float4 n0 = rp2[lane], n1 = rp2[64 + lane], n2 = rp2[128 + lane];
        float part = dot4(c0, aw0) + dot4(c1, aw1) + dot4(c2, aw2);
        #pragma unroll
        for (int off = 32; off; off >>= 1) part += __shfl_xor(part, off);
        float w = __expf(part);            // |score| small -> no max-sub needed
        lsum += w;
        fma4(p0, w, c0); fma4(p1, w, c1); fma4(p2, w, c2);
        c0 = n0; c1 = n1; c2 = n2;
      }
      float part = dot4(c0, aw0) + dot4(c1, aw1) + dot4(c2, aw2);
      #pragma unroll
      for (int off = 32; off; off >>= 1) part += __shfl_xor(part, off);
      float w = __expf(part);
      lsum += w;
      fma4(p0, w, c0); fma4(p1, w, c1); fma4(p2, w, c2);
    }
    ((float4*)sm.pool.pbuf[wid])[lane] = p0;
    ((float4*)sm.pool.pbuf[wid])[64 + lane] = p1;
    ((float4*)sm.pool.pbuf[wid])[128 + lane] = p2;
    if (lane == 0) sm.pool.sbuf[wid] = lsum;
    __syncthreads();
    float total = sm.pool.sbuf[0] + sm.pool.sbuf[1] + sm.pool.sbuf[2] + sm.pool.sbuf[3];
    if (total == 0.f) {                    // all rows masked: uniform alpha
      p0 = p1 = p2 = float4{0,0,0,0};
      for (int s = 0; s < 32; ++s) {
        const float4* rp = fb + (wid * 32 + s) * (En / 4);
        fma4(p0, 1.f, rp[lane]); fma4(p1, 1.f, rp[64 + lane]); fma4(p2, 1.f, rp[128 + lane]);
      }
      ((float4*)sm.pool.pbuf[wid])[lane] = p0;
      ((float4*)sm.pool.pbuf[wid])[64 + lane] = p1;
      ((float4*)sm.pool.pbuf[wid])[128 + lane] = p2;
      __syncthreads();
      total = 128.f;
    }
    const float inv = 1.f / total;
    if (t < 192) {
      float4 s0 = ((const float4*)sm.pool.pbuf[0])[t];
      float4 s1 = ((const float4*)sm.pool.pbuf[1])[t];
      float4 s2 = ((const float4*)sm.pool.pbuf[2])[t];
      float4 s3 = ((const float4*)sm.pool.pbuf[3])[t];
      ushort4 u4;
      u4.x = f2bf((s0.x+s1.x+s2.x+s3.x) * inv);
      u4.y = f2bf((s0.y+s1.y+s2.y+s3.y) * inv);
      u4.z = f2bf((s0.z+s1.z+s2.z+s3.z) * inv);
      u4.w = f2bf((s0.w+s1.w+s2.w+s3.w) * inv);
      ((ushort4*)pooled)[(size_t)b * 192 + t] = u4;
    }
    __syncthreads();
    if (t == 0) {
      __threadfence();
      aadd(&flags[F_TILE + (b >> 7)], 1);
      aadd(&flags[F_POOLALL], 1);
    }
  }

  // ================= phase 3: gemm units (spin on readiness) ===============
  const int r = t >> 2, c0i = (t & 3) * 8;
  const int wm = wid >> 1, wn = wid & 1;
  const int arow = wm * 64 + (lane & 15);
  const int aq = (lane >> 4) * 8;
  const int lrb = wm * 64 + ((lane >> 4) << 2);
  const int cb = wn * 64 + (lane & 15);
  for (;;) {
    __syncthreads();
    if (t == 0) curu = __hip_atomic_fetch_add(&flags[F_TGEMM], 1, __ATOMIC_RELAXED, __HIP_MEMORY_SCOPE_AGENT);
    __syncthreads();
    const int u = curu;
    if (u >= 480 + 3 * MAXTILES) break;
    f32x4 acc[4][4] = {};
    if (u < 480) {                         // -------------- gemme ----------
      const int bx = u % 15, by = u / 15;
      if (t == 0) {
        while (aload(&flags[F_PACKDONE]) < 2017 || aload(&flags[F_TILE + by]) < 128)
          __builtin_amdgcn_s_sleep(8);
        __threadfence();
      }
      __syncthreads();
      const int m0 = by * 128, ntg0 = bx * 8;
      for (int idx = t; idx < NHn * HIDn; idx += 256) sm.gemm.u.e.hwlds[idx] = hw[idx];
      for (int kt = 0; kt < 24; ++kt) {
        __syncthreads();
        *(uint4*)&sm.gemm.Alds[r * 40 + c0i] =
            *(const uint4*)&pooled[(size_t)(m0 + r) * En + kt * 32 + c0i];
        *(uint4*)&sm.gemm.Alds[(r + 64) * 40 + c0i] =
            *(const uint4*)&pooled[(size_t)(m0 + r + 64) * En + kt * 32 + c0i];
        #pragma unroll
        for (int rnd = 0; rnd < 2; ++rnd) {
          int chunk = t + rnd * 256;
          int nt = chunk >> 6, l2 = chunk & 63;
          *(uint4*)&sm.gemm.Blds[nt * 512 + l2 * 8] =
              *(const uint4*)&Bpe[((size_t)(ntg0 + nt) * 24 + kt) * 512 + l2 * 8];
        }
        __syncthreads();
        short8 af[4], bfv[4];
        #pragma unroll
        for (int i = 0; i < 4; ++i) af[i] = *(const short8*)&sm.gemm.Alds[(arow + i * 16) * 40 + aq];
        #pragma unroll
        for (int i = 0; i < 4; ++i) bfv[i] = *(const short8*)&sm.gemm.Blds[(wn * 4 + i) * 512 + lane * 8];
        #pragma unroll
        for (int i = 0; i < 4; ++i)
          #pragma unroll
          for (int jj = 0; jj < 4; ++jj)
            acc[i][jj] = __builtin_amdgcn_mfma_f32_16x16x32_bf16(af[i], bfv[jj], acc[i][jj], 0, 0, 0);
      }
      const int lcolbase = (bx % 3) * 128;
      float sums[4][4];
      #pragma unroll
      for (int i = 0; i < 4; ++i) {
        #pragma unroll
        for (int rr = 0; rr < 4; ++rr) {
          const int row = m0 + lrb + i * 16 + rr;
          const int cat = category[row];
          float s = 0.f;
          #pragma unroll
          for (int jj = 0; jj < 4; ++jj) {
            int cl = cb + jj * 16;
            float v = acc[i][jj][rr] + eb[bx * 128 + cl];
            v = fmaxf(v, 0.f);
            s = fmaf(v, sm.gemm.u.e.hwlds[cat * HIDn + lcolbase + cl], s);
          }
          #pragma unroll
          for (int off = 8; off; off >>= 1) s += __shfl_xor(s, off);
          sums[i][rr] = s;
        }
      }
      __syncthreads();
      if ((lane & 15) == 0) {
        #pragma unroll
        for (int i = 0; i < 4; ++i)
          #pragma unroll
          for (int rr = 0; rr < 4; ++rr)
            sm.gemm.u.e.plds[wn][lrb + i * 16 + rr] = sums[i][rr];
      }
      __syncthreads();
      if (t < 128) partial[(size_t)bx * Bn + m0 + t] = sm.gemm.u.e.plds[0][t] + sm.gemm.u.e.plds[1][t];
    } else {                               // -------------- gemmg ----------
      const int gid = u - 480;
      const int mt = gid / 3, bxg = gid % 3;
      if (t == 0) {
        while (aload(&flags[F_PACKDONE]) < 2017 || aload(&flags[F_POOLALL]) < Bn)
          __builtin_amdgcn_s_sleep(8);
        __threadfence();
      }
      __syncthreads();
      if (mt < meta[0]) {
        const int h = meta[1 + mt], valid = meta[64 + mt];
        if (t < 128) sm.gemm.u.g.rs[t] = rowsamp[mt * 128 + t];
        const float* w2src = g2 + ((size_t)h * HIDn + bxg * 128) * 5;
        for (int idx = t; idx < 640; idx += 256) sm.gemm.u.g.w2lds[idx] = w2src[idx];
        for (int kt = 0; kt < 24; ++kt) {
          __syncthreads();
          *(uint4*)&sm.gemm.Alds[r * 40 + c0i] =
              *(const uint4*)&pooled[(size_t)sm.gemm.u.g.rs[r] * En + kt * 32 + c0i];
          *(uint4*)&sm.gemm.Alds[(r + 64) * 40 + c0i] =
              *(const uint4*)&pooled[(size_t)sm.gemm.u.g.rs[r + 64] * En + kt * 32 + c0i];
          #pragma unroll
          for (int rnd = 0; rnd < 2; ++rnd) {
            int chunk = t + rnd * 256;
            int nt = chunk >> 6, l2 = chunk & 63;
            *(uint4*)&sm.gemm.Blds[nt * 512 + l2 * 8] =
                *(const uint4*)&Bpg[((size_t)(h * 24 + bxg * 8 + nt) * 24 + kt) * 512 + l2 * 8];
          }
          __syncthreads();
          short8 af[4], bfv[4];
          #pragma unroll
          for (int i = 0; i < 4; ++i) af[i] = *(const short8*)&sm.gemm.Alds[(arow + i * 16) * 40 + aq];
          #pragma unroll
          for (int i = 0; i < 4; ++i) bfv[i] = *(const short8*)&sm.gemm.Blds[(wn * 4 + i) * 512 + lane * 8];
          #pragma unroll
          for (int i = 0; i < 4; ++i)
            #pragma unroll
            for (int jj = 0; jj < 4; ++jj)
              acc[i][jj] = __builtin_amdgcn_mfma_f32_16x16x32_bf16(af[i], bfv[jj], acc[i][jj], 0, 0, 0);
        }
        #pragma unroll
        for (int i = 0; i < 4; ++i) {
          #pragma unroll
          for (int rr = 0; rr < 4; ++rr) {
            const int lrow = lrb + i * 16 + rr;
            float s[5] = {0.f, 0.f, 0.f, 0.f, 0.f};
            #pragma unroll
            for (int jj = 0; jj < 4; ++jj) {
              int cl = cb + jj * 16;
              float v = acc[i][jj][rr] + gb1[h * HIDn + bxg * 128 + cl];
              v = fmaxf(v, 0.f);
              #pragma unroll
              for (int k = 0; k < 5; ++k) s[k] = fmaf(v, sm.gemm.u.g.w2lds[cl * 5 + k], s[k]);
            }
            #pragma unroll
            for (int k = 0; k < 5; ++k)
              #pragma unroll
              for (int off = 8; off; off >>= 1) s[k] += __shfl_xor(s[k], off);
            if ((lane & 15) == 0 && lrow < valid) {
              int samp = sm.gemm.u.g.rs[lrow];
              #pragma unroll
              for (int k = 0; k < 5; ++k)
                glogp[((size_t)bxg * Bn + samp) * 5 + k] = s[k];
            }
          }
        }
      }
    }
  }
}

// ====== K3: gate softmax + expert combine + head bias + sigmoid ============
__global__ __launch_bounds__(256) void final_kernel(
    const float* __restrict__ partial, const float* __restrict__ glogp,
    const float* __restrict__ gb2, const int* __restrict__ category,
    const float* __restrict__ hb, float* __restrict__ out) {
  const int row = blockIdx.x * 256 + threadIdx.x;
  const int cat = category[row];
  float gl[5];
  #pragma unroll
  for (int k = 0; k < 5; ++k)
    gl[k] = gb2[cat * 5 + k]
          + glogp[((size_t)0 * Bn + row) * 5 + k]
          + glogp[((size_t)1 * Bn + row) * 5 + k]
          + glogp[((size_t)2 * Bn + row) * 5 + k];
  float mx = fmaxf(fmaxf(fmaxf(gl[0], gl[1]), fmaxf(gl[2], gl[3])), gl[4]);
  float ek[5], es = 0.f;
  #pragma unroll
  for (int k = 0; k < 5; ++k) { ek[k] = __expf(gl[k] - mx); es += ek[k]; }
  const float einv = 1.f / es;
  float s = 0.f;
  #pragma unroll
  for (int k = 0; k < 5; ++k) {
    float ps = partial[(size_t)(3 * k) * Bn + row]
             + partial[(size_t)(3 * k + 1) * Bn + row]
             + partial[(size_t)(3 * k + 2) * Bn + row];
    s = fmaf(ek[k] * einv, ps, s);
  }
  s += hb[cat];
  out[row] = 1.f / (1.f + __expf(-s));
}

extern "C" void kernel_launch(void* const* d_in, const int* in_sizes, int n_in,
                              void* d_out, int out_size, void* d_ws, size_t ws_size,
                              hipStream_t stream) {
  const float* feature  = (const float*)d_in[0];
  const int*   masks    = (const int*)d_in[1];
  const int*   category = (const int*)d_in[2];
  const float* attn_w   = (const float*)d_in[3];
  // d_in[4] attn_b cancels in softmax
  const float* gate_w1  = (const float*)d_in[5];
  const float* gate_b1  = (const float*)d_in[6];
  const float* gate_w2  = (const float*)d_in[7];
  const float* gate_b2  = (const float*)d_in[8];
  const float* expert_w = (const float*)d_in[9];
  const float* expert_b = (const float*)d_in[10];
  const float* head_w   = (const float*)d_in[11];
  const float* head_b   = (const float*)d_in[12];
  float* out = (float*)d_out;

  char* ws = (char*)d_ws;
  unsigned short* pooled = (unsigned short*)(ws);             //  6,291,456 B
  unsigned short* Bpe    = (unsigned short*)(ws + 6291456);   //  2,949,120 B
  unsigned short* Bpg    = (unsigned short*)(ws + 9240576);   //  5,308,416 B
  int* rowsamp           = (int*)(ws + 14548992);             //     20,992 B
  int* meta              = (int*)(ws + 14569984);             //        512 B
  float* glogp           = (float*)(ws + 14570496);           //    245,760 B
  float* partial         = (float*)(ws + 14816256);           //    245,760 B
  int* flags             = (int*)(ws + 15062016);             //        256 B

  zero_kernel<<<dim3(1), dim3(64), 0, stream>>>(flags);
  mega_kernel<<<dim3(NBLK), dim3(256), 0, stream>>>(
      feature, masks, attn_w, expert_w, gate_w1, category,
      gate_b1, gate_w2, expert_b, head_w,
      pooled, Bpe, Bpg, rowsamp, meta, partial, glogp, flags);
  final_kernel<<<dim3(16), dim3(256), 0, stream>>>(
      partial, glogp, gate_b2, category, head_b, out);
}

// Round 7
// 230.916 us; speedup vs baseline: 3.5539x; 3.5539x over previous
//
#include <hip/hip_runtime.h>
#include <hip/hip_bf16.h>

#define Bn   4096
#define Sn   128
#define En   768
#define HIDn 384
#define NHn  9
#define NEn  5
#define MAXTILES 41

typedef __attribute__((ext_vector_type(8))) short short8;
typedef __attribute__((ext_vector_type(4))) float f32x4;

__device__ __forceinline__ unsigned short f2bf(float v) {
  unsigned int x = __float_as_uint(v);
  x += 0x7fffu + ((x >> 16) & 1u);   // RNE
  return (unsigned short)(x >> 16);
}
__device__ __forceinline__ float dot4(float4 a, float4 b) {
  return fmaf(a.x, b.x, fmaf(a.y, b.y, fmaf(a.z, b.z, a.w * b.w)));
}
__device__ __forceinline__ void fma4(float4& p, float w, float4 v) {
  p.x = fmaf(w, v.x, p.x); p.y = fmaf(w, v.y, p.y);
  p.z = fmaf(w, v.z, p.z); p.w = fmaf(w, v.w, p.w);
}

// async global->LDS, 16B per lane. LDS base must be wave-uniform; hardware
// writes lane l at ldsbase + l*16. Global pointer is per-lane.
#if defined(__has_builtin) && __has_builtin(__builtin_amdgcn_global_load_lds)
#define HAVE_GLOAD_LDS 1
__device__ __forceinline__ void gload16(const unsigned short* g, unsigned short* l) {
  __builtin_amdgcn_global_load_lds(
      (const __attribute__((address_space(1))) unsigned int*)g,
      (__attribute__((address_space(3))) unsigned int*)l, 16, 0, 0);
}
#else
#define HAVE_GLOAD_LDS 0
#endif

// ====== K1: pool (blocks 0..4095) | pack (4096..6111) | sort (6112) =========
__global__ __launch_bounds__(256) void prep_kernel(
    const float* __restrict__ feature, const int* __restrict__ masks,
    const float* __restrict__ attn_w, const float* __restrict__ ew,
    const float* __restrict__ g1, const int* __restrict__ category,
    unsigned short* __restrict__ pooled, unsigned short* __restrict__ Ape,
    unsigned short* __restrict__ Bpe, unsigned short* __restrict__ Bpg,
    int* __restrict__ rowsamp, int* __restrict__ meta) {
  __shared__ __align__(16) union {
    struct { float pbuf[4][768]; float sbuf[4]; } pool;
    struct { int hist[NHn][256]; int padbase[NHn]; int total[NHn];
             int tilecat[MAXTILES]; int padTiles; } srt;
  } sm;
  const int t = threadIdx.x, lane = t & 63, wid = t >> 6;
  const int bid = blockIdx.x;

  if (bid < Bn) {                          // ---------------- pool ----------
    const int b = bid;
    const float4* aw = (const float4*)attn_w;
    const float4 aw0 = aw[lane], aw1 = aw[64 + lane], aw2 = aw[128 + lane];
    const float4* fb = (const float4*)(feature + (size_t)b * (Sn * En));
    unsigned long long bal = __ballot(lane < 32 && masks[b * Sn + wid * 32 + (lane & 31)] != 0);
    unsigned int m = (unsigned int)bal;
    float4 p0 = {0,0,0,0}, p1 = {0,0,0,0}, p2 = {0,0,0,0};
    float lsum = 0.f;
    if (m) {
      int s = __builtin_ctz(m); m &= m - 1;
      const float4* rp = fb + (wid * 32 + s) * (En / 4);
      float4 c0 = rp[lane], c1 = rp[64 + lane], c2 = rp[128 + lane];
      while (m) {
        int s2 = __builtin_ctz(m); m &= m - 1;
        const float4* rp2 = fb + (wid * 32 + s2) * (En / 4);
        float4 n0 = rp2[lane], n1 = rp2[64 + lane], n2 = rp2[128 + lane];
        float part = dot4(c0, aw0) + dot4(c1, aw1) + dot4(c2, aw2);
        #pragma unroll
        for (int off = 32; off; off >>= 1) part += __shfl_xor(part, off);
        float w = __expf(part);            // |score| small -> no max-sub needed
        lsum += w;
        fma4(p0, w, c0); fma4(p1, w, c1); fma4(p2, w, c2);
        c0 = n0; c1 = n1; c2 = n2;
      }
      float part = dot4(c0, aw0) + dot4(c1, aw1) + dot4(c2, aw2);
      #pragma unroll
      for (int off = 32; off; off >>= 1) part += __shfl_xor(part, off);
      float w = __expf(part);
      lsum += w;
      fma4(p0, w, c0); fma4(p1, w, c1); fma4(p2, w, c2);
    }
    ((float4*)sm.pool.pbuf[wid])[lane] = p0;
    ((float4*)sm.pool.pbuf[wid])[64 + lane] = p1;
    ((float4*)sm.pool.pbuf[wid])[128 + lane] = p2;
    if (lane == 0) sm.pool.sbuf[wid] = lsum;
    __syncthreads();
    float total = sm.pool.sbuf[0] + sm.pool.sbuf[1] + sm.pool.sbuf[2] + sm.pool.sbuf[3];
    if (total == 0.f) {                    // all rows masked: uniform alpha
      p0 = p1 = p2 = float4{0,0,0,0};
      for (int s = 0; s < 32; ++s) {
        const float4* rp = fb + (wid * 32 + s) * (En / 4);
        fma4(p0, 1.f, rp[lane]); fma4(p1, 1.f, rp[64 + lane]); fma4(p2, 1.f, rp[128 + lane]);
      }
      ((float4*)sm.pool.pbuf[wid])[lane] = p0;
      ((float4*)sm.pool.pbuf[wid])[64 + lane] = p1;
      ((float4*)sm.pool.pbuf[wid])[128 + lane] = p2;
      __syncthreads();
      total = 128.f;
    }
    const float inv = 1.f / total;
    if (t < 192) {                         // elems k = 4t..4t+3
      float4 s0 = ((const float4*)sm.pool.pbuf[0])[t];
      float4 s1 = ((const float4*)sm.pool.pbuf[1])[t];
      float4 s2 = ((const float4*)sm.pool.pbuf[2])[t];
      float4 s3 = ((const float4*)sm.pool.pbuf[3])[t];
      ushort4 u4;
      u4.x = f2bf((s0.x+s1.x+s2.x+s3.x) * inv);
      u4.y = f2bf((s0.y+s1.y+s2.y+s3.y) * inv);
      u4.z = f2bf((s0.z+s1.z+s2.z+s3.z) * inv);
      u4.w = f2bf((s0.w+s1.w+s2.w+s3.w) * inv);
      ((ushort4*)pooled)[(size_t)b * 192 + t] = u4;
      // A-fragment copy: Ape[(s*24+kt)*512 + lane8*8 + e] = A[16s+(b&15)][kt*32+(lane8>>4)*8+e]
      const int kt = t >> 3, q = (t >> 1) & 3, e = (t & 1) * 4;
      *(ushort4*)&Ape[((size_t)(b >> 4) * 24 + kt) * 512 + ((b & 15) + (q << 4)) * 8 + e] = u4;
    }
    return;
  }

  if (bid < Bn + 2016) {                   // ---------------- pack ----------
    const int pair = (bid - Bn) * 4 + wid;
    const int q = lane >> 4, j = lane & 15;
    const float* src; unsigned short* dst; int kt;
    if (pair < 2880) {                     // expert: 120 ntiles x 24 kt
      int nt = pair / 24; kt = pair % 24;
      int col = nt * 16 + j;
      src = ew + (size_t)(col / HIDn) * (En * HIDn) + (col % HIDn);
      dst = Bpe + (size_t)pair * 512;
    } else {                               // gate: 9 heads x 24 ntiles x 24 kt
      int g = pair - 2880;
      int h = g / 576, rem = g % 576;
      int nt = rem / 24; kt = rem % 24;
      int col = nt * 16 + j;
      src = g1 + (size_t)h * (En * HIDn) + col;
      dst = Bpg + ((size_t)(h * 24 + nt) * 24 + kt) * 512;
    }
    unsigned short outv[8] __attribute__((aligned(16)));
    #pragma unroll
    for (int e = 0; e < 8; ++e) {
      int k = kt * 32 + q * 8 + e;
      outv[e] = f2bf(src[(size_t)k * HIDn]);
    }
    *(uint4*)&dst[lane * 8] = *(const uint4*)outv;
    return;
  }

  // -------- sort: stable counting sort by category, 128-padded tiles -------
  #pragma unroll
  for (int jj = 0; jj < NHn; ++jj) sm.srt.hist[jj][t] = 0;
  __syncthreads();
  for (int i = 0; i < 16; ++i) { int c = category[t * 16 + i]; sm.srt.hist[c][t]++; }
  __syncthreads();
  if (t < NHn) {
    int run = 0;
    for (int x = 0; x < 256; ++x) { int v = sm.srt.hist[t][x]; sm.srt.hist[t][x] = run; run += v; }
    sm.srt.total[t] = run;
  }
  __syncthreads();
  if (t == 0) {
    int pb = 0, mt = 0;
    for (int jj = 0; jj < NHn; ++jj) {
      sm.srt.padbase[jj] = pb;
      int tot = sm.srt.total[jj];
      int nt = (tot + 127) >> 7;
      for (int k2 = 0; k2 < nt; ++k2) {
        meta[1 + mt + k2] = jj;
        int vv = tot - (k2 << 7); if (vv > 128) vv = 128;
        meta[64 + mt + k2] = vv;
        sm.srt.tilecat[mt + k2] = jj;
      }
      mt += nt; pb += nt << 7;
    }
    meta[0] = mt; sm.srt.padTiles = mt;
  }
  __syncthreads();
  const int padM = sm.srt.padTiles << 7;
  for (int mm = t; mm < padM; mm += 256) {
    int h = sm.srt.tilecat[mm >> 7];
    if (mm - sm.srt.padbase[h] >= sm.srt.total[h]) rowsamp[mm] = 0;
  }
  for (int i = 0; i < 16; ++i) {           // stable scatter
    int idx = t * 16 + i; int c = category[idx];
    int off = sm.srt.hist[c][t]++;
    rowsamp[sm.srt.padbase[c] + off] = idx;
  }
}

// ====== K2: gemme (blocks 0..479, frag A + global_load_lds) |
//            gemmg (480..602, gathered A via padded LDS) ====================
__global__ __launch_bounds__(256) void gemm_kernel(
    const unsigned short* __restrict__ pooled, const unsigned short* __restrict__ Ape,
    const unsigned short* __restrict__ Bpe, const unsigned short* __restrict__ Bpg,
    const float* __restrict__ eb, const float* __restrict__ gb1,
    const float* __restrict__ g2, const int* __restrict__ category,
    const float* __restrict__ hw, const int* __restrict__ rowsamp,
    const int* __restrict__ meta, float* __restrict__ partial,
    float* __restrict__ glogp) {
  __shared__ __align__(16) union {
    struct { unsigned short Af[4096]; unsigned short Bf[4096]; float plds[2][128]; } e;
    struct { unsigned short Ap[128 * 40]; unsigned short Bf[4096];
             int rs[128]; float w2[640]; } g;
  } sm;
  const int t = threadIdx.x, lane = t & 63, wid = t >> 6;
  const int wm = wid >> 1, wn = wid & 1;
  const int bid = blockIdx.x;
  const int lrb = wm * 64 + ((lane >> 4) << 2);
  const int cb = wn * 64 + (lane & 15);
  f32x4 acc[4][4] = {};

  if (bid < 480) {                         // -------------- gemme ----------
    const int bx = bid % 15, by = bid / 15;
    const int m0 = by * 128, ntg0 = bx * 8;
    for (int kt = 0; kt < 24; ++kt) {
      __syncthreads();
      #pragma unroll
      for (int rnd = 0; rnd < 2; ++rnd) {
        const int st = wid * 2 + rnd;      // wave-uniform subtile 0..7
#if HAVE_GLOAD_LDS
        gload16(&Ape[((size_t)(by * 8 + st) * 24 + kt) * 512 + lane * 8], &sm.e.Af[st * 512]);
        gload16(&Bpe[((size_t)(ntg0 + st) * 24 + kt) * 512 + lane * 8], &sm.e.Bf[st * 512]);
#else
        *(uint4*)&sm.e.Af[st * 512 + lane * 8] =
            *(const uint4*)&Ape[((size_t)(by * 8 + st) * 24 + kt) * 512 + lane * 8];
        *(uint4*)&sm.e.Bf[st * 512 + lane * 8] =
            *(const uint4*)&Bpe[((size_t)(ntg0 + st) * 24 + kt) * 512 + lane * 8];
#endif
      }
      __syncthreads();
      short8 af[4], bfv[4];
      #pragma unroll
      for (int i = 0; i < 4; ++i) af[i] = *(const short8*)&sm.e.Af[(wm * 4 + i) * 512 + lane * 8];
      #pragma unroll
      for (int i = 0; i < 4; ++i) bfv[i] = *(const short8*)&sm.e.Bf[(wn * 4 + i) * 512 + lane * 8];
      #pragma unroll
      for (int i = 0; i < 4; ++i)
        #pragma unroll
        for (int jj = 0; jj < 4; ++jj)
          acc[i][jj] = __builtin_amdgcn_mfma_f32_16x16x32_bf16(af[i], bfv[jj], acc[i][jj], 0, 0, 0);
    }
    const int lcolbase = (bx % 3) * 128;
    float sums[4][4];
    #pragma unroll
    for (int i = 0; i < 4; ++i) {
      #pragma unroll
      for (int rr = 0; rr < 4; ++rr) {
        const int row = m0 + lrb + i * 16 + rr;
        const int cat = category[row];
        float s = 0.f;
        #pragma unroll
        for (int jj = 0; jj < 4; ++jj) {
          int cl = cb + jj * 16;
          float v = acc[i][jj][rr] + eb[bx * 128 + cl];
          v = fmaxf(v, 0.f);
          s = fmaf(v, hw[cat * HIDn + lcolbase + cl], s);
        }
        #pragma unroll
        for (int off = 8; off; off >>= 1) s += __shfl_xor(s, off);
        sums[i][rr] = s;
      }
    }
    __syncthreads();
    if ((lane & 15) == 0) {
      #pragma unroll
      for (int i = 0; i < 4; ++i)
        #pragma unroll
        for (int rr = 0; rr < 4; ++rr)
          sm.e.plds[wn][lrb + i * 16 + rr] = sums[i][rr];
    }
    __syncthreads();
    if (t < 128) partial[(size_t)bx * Bn + m0 + t] = sm.e.plds[0][t] + sm.e.plds[1][t];
    return;
  }

  // ---------------- gemmg: sorted-gather gate GEMM + W2 epilogue ----------
  const int gid = bid - 480;
  const int mt = gid / 3, bxg = gid % 3;
  if (mt >= meta[0]) return;
  const int h = meta[1 + mt], valid = meta[64 + mt];
  const int r = t >> 2, c0i = (t & 3) * 8;
  const int arow = wm * 64 + (lane & 15);
  const int aq = (lane >> 4) * 8;
  if (t < 128) sm.g.rs[t] = rowsamp[mt * 128 + t];
  const float* w2src = g2 + ((size_t)h * HIDn + bxg * 128) * 5;
  for (int idx = t; idx < 640; idx += 256) sm.g.w2[idx] = w2src[idx];
  for (int kt = 0; kt < 24; ++kt) {
    __syncthreads();
    *(uint4*)&sm.g.Ap[r * 40 + c0i] =
        *(const uint4*)&pooled[(size_t)sm.g.rs[r] * En + kt * 32 + c0i];
    *(uint4*)&sm.g.Ap[(r + 64) * 40 + c0i] =
        *(const uint4*)&pooled[(size_t)sm.g.rs[r + 64] * En + kt * 32 + c0i];
    #pragma unroll
    for (int rnd = 0; rnd < 2; ++rnd) {
      const int st = wid * 2 + rnd;
#if HAVE_GLOAD_LDS
      gload16(&Bpg[((size_t)(h * 24 + bxg * 8 + st) * 24 + kt) * 512 + lane * 8], &sm.g.Bf[st * 512]);
#else
      *(uint4*)&sm.g.Bf[st * 512 + lane * 8] =
          *(const uint4*)&Bpg[((size_t)(h * 24 + bxg * 8 + st) * 24 + kt) * 512 + lane * 8];
#endif
    }
    __syncthreads();
    short8 af[4], bfv[4];
    #pragma unroll
    for (int i = 0; i < 4; ++i) af[i] = *(const short8*)&sm.g.Ap[(arow + i * 16) * 40 + aq];
    #pragma unroll
    for (int i = 0; i < 4; ++i) bfv[i] = *(const short8*)&sm.g.Bf[(wn * 4 + i) * 512 + lane * 8];
    #pragma unroll
    for (int i = 0; i < 4; ++i)
      #pragma unroll
      for (int jj = 0; jj < 4; ++jj)
        acc[i][jj] = __builtin_amdgcn_mfma_f32_16x16x32_bf16(af[i], bfv[jj], acc[i][jj], 0, 0, 0);
  }
  #pragma unroll
  for (int i = 0; i < 4; ++i) {
    #pragma unroll
    for (int rr = 0; rr < 4; ++rr) {
      const int lrow = lrb + i * 16 + rr;
      float s[5] = {0.f, 0.f, 0.f, 0.f, 0.f};
      #pragma unroll
      for (int jj = 0; jj < 4; ++jj) {
        int cl = cb + jj * 16;
        float v = acc[i][jj][rr] + gb1[h * HIDn + bxg * 128 + cl];
        v = fmaxf(v, 0.f);
        #pragma unroll
        for (int k = 0; k < 5; ++k) s[k] = fmaf(v, sm.g.w2[cl * 5 + k], s[k]);
      }
      #pragma unroll
      for (int k = 0; k < 5; ++k)
        #pragma unroll
        for (int off = 8; off; off >>= 1) s[k] += __shfl_xor(s[k], off);
      if ((lane & 15) == 0 && lrow < valid) {
        int samp = sm.g.rs[lrow];
        #pragma unroll
        for (int k = 0; k < 5; ++k)
          glogp[((size_t)bxg * Bn + samp) * 5 + k] = s[k];
      }
    }
  }
}

// ====== K3: gate softmax + expert combine + head bias + sigmoid ============
__global__ __launch_bounds__(256) void final_kernel(
    const float* __restrict__ partial, const float* __restrict__ glogp,
    const float* __restrict__ gb2, const int* __restrict__ category,
    const float* __restrict__ hb, float* __restrict__ out) {
  const int row = blockIdx.x * 256 + threadIdx.x;
  const int cat = category[row];
  float gl[5];
  #pragma unroll
  for (int k = 0; k < 5; ++k)
    gl[k] = gb2[cat * 5 + k]
          + glogp[((size_t)0 * Bn + row) * 5 + k]
          + glogp[((size_t)1 * Bn + row) * 5 + k]
          + glogp[((size_t)2 * Bn + row) * 5 + k];
  float mx = fmaxf(fmaxf(fmaxf(gl[0], gl[1]), fmaxf(gl[2], gl[3])), gl[4]);
  float ek[5], es = 0.f;
  #pragma unroll
  for (int k = 0; k < 5; ++k) { ek[k] = __expf(gl[k] - mx); es += ek[k]; }
  const float einv = 1.f / es;
  float s = 0.f;
  #pragma unroll
  for (int k = 0; k < 5; ++k) {
    float ps = partial[(size_t)(3 * k) * Bn + row]
             + partial[(size_t)(3 * k + 1) * Bn + row]
             + partial[(size_t)(3 * k + 2) * Bn + row];
    s = fmaf(ek[k] * einv, ps, s);
  }
  s += hb[cat];
  out[row] = 1.f / (1.f + __expf(-s));
}

extern "C" void kernel_launch(void* const* d_in, const int* in_sizes, int n_in,
                              void* d_out, int out_size, void* d_ws, size_t ws_size,
                              hipStream_t stream) {
  const float* feature  = (const float*)d_in[0];
  const int*   masks    = (const int*)d_in[1];
  const int*   category = (const int*)d_in[2];
  const float* attn_w   = (const float*)d_in[3];
  // d_in[4] attn_b cancels in softmax
  const float* gate_w1  = (const float*)d_in[5];
  const float* gate_b1  = (const float*)d_in[6];
  const float* gate_w2  = (const float*)d_in[7];
  const float* gate_b2  = (const float*)d_in[8];
  const float* expert_w = (const float*)d_in[9];
  const float* expert_b = (const float*)d_in[10];
  const float* head_w   = (const float*)d_in[11];
  const float* head_b   = (const float*)d_in[12];
  float* out = (float*)d_out;

  char* ws = (char*)d_ws;
  unsigned short* pooled = (unsigned short*)(ws);             //  6,291,456 B
  unsigned short* Ape    = (unsigned short*)(ws + 6291456);   //  6,291,456 B
  unsigned short* Bpe    = (unsigned short*)(ws + 12582912);  //  2,949,120 B
  unsigned short* Bpg    = (unsigned short*)(ws + 15532032);  //  5,308,416 B
  int* rowsamp           = (int*)(ws + 20840448);             //     20,992 B
  int* meta              = (int*)(ws + 20861440);             //        512 B
  float* glogp           = (float*)(ws + 20861952);           //    245,760 B
  float* partial         = (float*)(ws + 21107712);           //    245,760 B

  prep_kernel<<<dim3(Bn + 2016 + 1), dim3(256), 0, stream>>>(
      feature, masks, attn_w, expert_w, gate_w1, category,
      pooled, Ape, Bpe, Bpg, rowsamp, meta);
  gemm_kernel<<<dim3(480 + 3 * MAXTILES), dim3(256), 0, stream>>>(
      pooled, Ape, Bpe, Bpg, expert_b, gate_b1, gate_w2, category, head_w,
      rowsamp, meta, partial, glogp);
  final_kernel<<<dim3(16), dim3(256), 0, stream>>>(
      partial, glogp, gate_b2, category, head_b, out);
}

// Round 8
// 183.947 us; speedup vs baseline: 4.4614x; 1.2553x over previous
//
#include <hip/hip_runtime.h>
#include <hip/hip_bf16.h>

#define Bn   4096
#define Sn   128
#define En   768
#define HIDn 384
#define NHn  9
#define NEn  5
#define MAXTILES 41       // max padded m-tiles: 32 + up to 8 from per-cat rounding

typedef __attribute__((ext_vector_type(8))) short short8;
typedef __attribute__((ext_vector_type(4))) float f32x4;

__device__ __forceinline__ unsigned short f2bf(float v) {
  unsigned int x = __float_as_uint(v);
  x += 0x7fffu + ((x >> 16) & 1u);   // RNE
  return (unsigned short)(x >> 16);
}
__device__ __forceinline__ float dot4v(f32x4 a, f32x4 b) {
  return fmaf(a.x, b.x, fmaf(a.y, b.y, fmaf(a.z, b.z, a.w * b.w)));
}
__device__ __forceinline__ f32x4 ntl(const f32x4* p) {
  return __builtin_nontemporal_load(p);   // streaming read, no L2 reuse
}

// process one feature row held in x0..x2 (12 floats/lane across 64 lanes)
#define PROC(x0, x1, x2) {                                                 \
    float part = dot4v(x0, aw0) + dot4v(x1, aw1) + dot4v(x2, aw2);         \
    _Pragma("unroll")                                                      \
    for (int off = 32; off; off >>= 1) part += __shfl_xor(part, off);      \
    float w = __expf(part);               /* |score| small: no max-sub */  \
    lsum += w;                                                             \
    p0 += w * (x0); p1 += w * (x1); p2 += w * (x2); }

// ====== K1: pool (blocks 0..4095) | pack (4096..6111) | sort (6112) =========
__global__ __launch_bounds__(256) void prep_kernel(
    const float* __restrict__ feature, const int* __restrict__ masks,
    const float* __restrict__ attn_w, const float* __restrict__ ew,
    const float* __restrict__ g1, const int* __restrict__ category,
    unsigned short* __restrict__ pooled, unsigned short* __restrict__ Bpe,
    unsigned short* __restrict__ Bpg, int* __restrict__ rowsamp,
    int* __restrict__ meta) {
  __shared__ __align__(16) union {
    struct { float pbuf[4][768]; float sbuf[4]; } pool;
    struct { int hist[NHn][256]; int padbase[NHn]; int total[NHn];
             int tilecat[MAXTILES]; int padTiles; } srt;
  } sm;
  const int t = threadIdx.x, lane = t & 63, wid = t >> 6;
  const int bid = blockIdx.x;

  if (bid < Bn) {                          // ---------------- pool ----------
    const int b = bid;
    const f32x4* aw = (const f32x4*)attn_w;
    const f32x4 aw0 = aw[lane], aw1 = aw[64 + lane], aw2 = aw[128 + lane];
    const f32x4* fb = (const f32x4*)(feature + (size_t)b * (Sn * En));
    unsigned long long bal = __ballot(lane < 32 && masks[b * Sn + wid * 32 + (lane & 31)] != 0);
    unsigned int m = (unsigned int)bal;
    const int rowbase = wid * 32;
    f32x4 p0 = {0,0,0,0}, p1 = {0,0,0,0}, p2 = {0,0,0,0};
    float lsum = 0.f;
    if (m) {                               // 2-deep software pipeline
      int s = __builtin_ctz(m); m &= m - 1;
      const f32x4* rp = fb + (rowbase + s) * 192;
      f32x4 a0 = ntl(rp + lane), a1 = ntl(rp + 64 + lane), a2 = ntl(rp + 128 + lane);
      if (m) {
        int s2 = __builtin_ctz(m); m &= m - 1;
        const f32x4* rq = fb + (rowbase + s2) * 192;
        f32x4 b0 = ntl(rq + lane), b1 = ntl(rq + 64 + lane), b2 = ntl(rq + 128 + lane);
        while (m) {
          int s3 = __builtin_ctz(m); m &= m - 1;
          const f32x4* rr = fb + (rowbase + s3) * 192;
          f32x4 n0 = ntl(rr + lane), n1 = ntl(rr + 64 + lane), n2 = ntl(rr + 128 + lane);
          PROC(a0, a1, a2);
          a0 = b0; a1 = b1; a2 = b2;
          b0 = n0; b1 = n1; b2 = n2;
        }
        PROC(a0, a1, a2);
        a0 = b0; a1 = b1; a2 = b2;
      }
      PROC(a0, a1, a2);
    }
    ((f32x4*)sm.pool.pbuf[wid])[lane] = p0;
    ((f32x4*)sm.pool.pbuf[wid])[64 + lane] = p1;
    ((f32x4*)sm.pool.pbuf[wid])[128 + lane] = p2;
    if (lane == 0) sm.pool.sbuf[wid] = lsum;
    __syncthreads();
    float total = sm.pool.sbuf[0] + sm.pool.sbuf[1] + sm.pool.sbuf[2] + sm.pool.sbuf[3];
    if (total == 0.f) {                    // all rows masked: uniform alpha
      p0 = p1 = p2 = f32x4{0,0,0,0};
      for (int s = 0; s < 32; ++s) {
        const f32x4* rp = fb + (rowbase + s) * 192;
        p0 += ntl(rp + lane); p1 += ntl(rp + 64 + lane); p2 += ntl(rp + 128 + lane);
      }
      ((f32x4*)sm.pool.pbuf[wid])[lane] = p0;
      ((f32x4*)sm.pool.pbuf[wid])[64 + lane] = p1;
      ((f32x4*)sm.pool.pbuf[wid])[128 + lane] = p2;
      __syncthreads();
      total = 128.f;
    }
    const float inv = 1.f / total;
    if (t < 192) {
      f32x4 s0 = ((const f32x4*)sm.pool.pbuf[0])[t];
      f32x4 s1 = ((const f32x4*)sm.pool.pbuf[1])[t];
      f32x4 s2 = ((const f32x4*)sm.pool.pbuf[2])[t];
      f32x4 s3 = ((const f32x4*)sm.pool.pbuf[3])[t];
      f32x4 smv = (s0 + s1) + (s2 + s3);
      ushort4 u4;
      u4.x = f2bf(smv.x * inv); u4.y = f2bf(smv.y * inv);
      u4.z = f2bf(smv.z * inv); u4.w = f2bf(smv.w * inv);
      ((ushort4*)pooled)[(size_t)b * 192 + t] = u4;
    }
    return;
  }

  if (bid < Bn + 2016) {                   // ---------------- pack ----------
    const int pair = (bid - Bn) * 4 + wid;
    const int q = lane >> 4, j = lane & 15;
    const float* src; unsigned short* dst; int kt;
    if (pair < 2880) {                     // expert: 120 ntiles x 24 kt
      int nt = pair / 24; kt = pair % 24;
      int col = nt * 16 + j;
      src = ew + (size_t)(col / HIDn) * (En * HIDn) + (col % HIDn);
      dst = Bpe + (size_t)pair * 512;
    } else {                               // gate: 9 heads x 24 ntiles x 24 kt
      int g = pair - 2880;
      int h = g / 576, rem = g % 576;
      int nt = rem / 24; kt = rem % 24;
      int col = nt * 16 + j;
      src = g1 + (size_t)h * (En * HIDn) + col;
      dst = Bpg + ((size_t)(h * 24 + nt) * 24 + kt) * 512;
    }
    unsigned short outv[8] __attribute__((aligned(16)));
    #pragma unroll
    for (int e = 0; e < 8; ++e) {
      int k = kt * 32 + q * 8 + e;
      outv[e] = f2bf(src[(size_t)k * HIDn]);
    }
    *(uint4*)&dst[lane * 8] = *(const uint4*)outv;
    return;
  }

  // -------- sort: stable counting sort by category, 128-padded tiles -------
  #pragma unroll
  for (int jj = 0; jj < NHn; ++jj) sm.srt.hist[jj][t] = 0;
  __syncthreads();
  for (int i = 0; i < 16; ++i) { int c = category[t * 16 + i]; sm.srt.hist[c][t]++; }
  __syncthreads();
  if (t < NHn) {
    int run = 0;
    for (int x = 0; x < 256; ++x) { int v = sm.srt.hist[t][x]; sm.srt.hist[t][x] = run; run += v; }
    sm.srt.total[t] = run;
  }
  __syncthreads();
  if (t == 0) {
    int pb = 0, mt = 0;
    for (int jj = 0; jj < NHn; ++jj) {
      sm.srt.padbase[jj] = pb;
      int tot = sm.srt.total[jj];
      int nt = (tot + 127) >> 7;
      for (int k2 = 0; k2 < nt; ++k2) {
        meta[1 + mt + k2] = jj;
        int vv = tot - (k2 << 7); if (vv > 128) vv = 128;
        meta[64 + mt + k2] = vv;
        sm.srt.tilecat[mt + k2] = jj;
      }
      mt += nt; pb += nt << 7;
    }
    meta[0] = mt; sm.srt.padTiles = mt;
  }
  __syncthreads();
  const int padM = sm.srt.padTiles << 7;
  for (int mm = t; mm < padM; mm += 256) {
    int h = sm.srt.tilecat[mm >> 7];
    if (mm - sm.srt.padbase[h] >= sm.srt.total[h]) rowsamp[mm] = 0;
  }
  for (int i = 0; i < 16; ++i) {           // stable scatter
    int idx = t * 16 + i; int c = category[idx];
    int off = sm.srt.hist[c][t]++;
    rowsamp[sm.srt.padbase[c] + off] = idx;
  }
}

// ====== K2: gemmg (blocks 0..122) | gemme (123..602), both LDS-staged ======
__global__ __launch_bounds__(256) void gemm_kernel(
    const unsigned short* __restrict__ pooled, const unsigned short* __restrict__ Bpe,
    const unsigned short* __restrict__ Bpg, const float* __restrict__ eb,
    const float* __restrict__ gb1, const float* __restrict__ g2,
    const int* __restrict__ category, const float* __restrict__ hw,
    const int* __restrict__ rowsamp, const int* __restrict__ meta,
    float* __restrict__ partial, float* __restrict__ glogp) {
  __shared__ __align__(16) struct {
    unsigned short Alds[128 * 40];
    unsigned short Blds[8 * 512];
    union {
      struct { float plds[2][128]; } e;
      struct { int rs[128]; float w2[640]; } g;
    } u;
  } sm;
  const int t = threadIdx.x, lane = t & 63, wid = t >> 6;
  const int wm = wid >> 1, wn = wid & 1;
  const int bid = blockIdx.x;
  const int r = t >> 2, c0 = (t & 3) * 8;
  const int arow = wm * 64 + (lane & 15);
  const int aq = (lane >> 4) * 8;
  const int lrb = wm * 64 + ((lane >> 4) << 2);
  const int cb = wn * 64 + (lane & 15);
  f32x4 acc[4][4] = {};

  if (bid < 3 * MAXTILES) {                // -------------- gemmg ----------
    const int mt = bid / 3, bxg = bid % 3;
    if (mt >= meta[0]) return;
    const int h = meta[1 + mt], valid = meta[64 + mt];
    if (t < 128) sm.u.g.rs[t] = rowsamp[mt * 128 + t];
    const float* w2src = g2 + ((size_t)h * HIDn + bxg * 128) * 5;
    for (int idx = t; idx < 640; idx += 256) sm.u.g.w2[idx] = w2src[idx];
    for (int kt = 0; kt < 24; ++kt) {
      __syncthreads();
      *(uint4*)&sm.Alds[r * 40 + c0] =
          *(const uint4*)&pooled[(size_t)sm.u.g.rs[r] * En + kt * 32 + c0];
      *(uint4*)&sm.Alds[(r + 64) * 40 + c0] =
          *(const uint4*)&pooled[(size_t)sm.u.g.rs[r + 64] * En + kt * 32 + c0];
      #pragma unroll
      for (int rnd = 0; rnd < 2; ++rnd) {
        int chunk = t + rnd * 256;
        int nt = chunk >> 6, l2 = chunk & 63;
        *(uint4*)&sm.Blds[nt * 512 + l2 * 8] =
            *(const uint4*)&Bpg[((size_t)(h * 24 + bxg * 8 + nt) * 24 + kt) * 512 + l2 * 8];
      }
      __syncthreads();
      short8 af[4], bfv[4];
      #pragma unroll
      for (int i = 0; i < 4; ++i) af[i] = *(const short8*)&sm.Alds[(arow + i * 16) * 40 + aq];
      #pragma unroll
      for (int i = 0; i < 4; ++i) bfv[i] = *(const short8*)&sm.Blds[(wn * 4 + i) * 512 + lane * 8];
      #pragma unroll
      for (int i = 0; i < 4; ++i)
        #pragma unroll
        for (int jj = 0; jj < 4; ++jj)
          acc[i][jj] = __builtin_amdgcn_mfma_f32_16x16x32_bf16(af[i], bfv[jj], acc[i][jj], 0, 0, 0);
    }
    #pragma unroll
    for (int i = 0; i < 4; ++i) {
      #pragma unroll
      for (int rr = 0; rr < 4; ++rr) {
        const int lrow = lrb + i * 16 + rr;
        float s[5] = {0.f, 0.f, 0.f, 0.f, 0.f};
        #pragma unroll
        for (int jj = 0; jj < 4; ++jj) {
          int cl = cb + jj * 16;
          float v = acc[i][jj][rr] + gb1[h * HIDn + bxg * 128 + cl];
          v = fmaxf(v, 0.f);
          #pragma unroll
          for (int k = 0; k < 5; ++k) s[k] = fmaf(v, sm.u.g.w2[cl * 5 + k], s[k]);
        }
        #pragma unroll
        for (int k = 0; k < 5; ++k)
          #pragma unroll
          for (int off = 8; off; off >>= 1) s[k] += __shfl_xor(s[k], off);
        if ((lane & 15) == 0 && lrow < valid) {
          int samp = sm.u.g.rs[lrow];
          #pragma unroll
          for (int k = 0; k < 5; ++k)
            glogp[((size_t)bxg * Bn + samp) * 5 + k] = s[k];
        }
      }
    }
    return;
  }

  // ---------------- gemme ----------
  const int e = bid - 3 * MAXTILES;
  const int bx = e % 15, by = e / 15;
  const int m0 = by * 128, ntg0 = bx * 8;
  for (int kt = 0; kt < 24; ++kt) {
    __syncthreads();
    *(uint4*)&sm.Alds[r * 40 + c0] =
        *(const uint4*)&pooled[(size_t)(m0 + r) * En + kt * 32 + c0];
    *(uint4*)&sm.Alds[(r + 64) * 40 + c0] =
        *(const uint4*)&pooled[(size_t)(m0 + r + 64) * En + kt * 32 + c0];
    #pragma unroll
    for (int rnd = 0; rnd < 2; ++rnd) {
      int chunk = t + rnd * 256;
      int nt = chunk >> 6, l2 = chunk & 63;
      *(uint4*)&sm.Blds[nt * 512 + l2 * 8] =
          *(const uint4*)&Bpe[((size_t)(ntg0 + nt) * 24 + kt) * 512 + l2 * 8];
    }
    __syncthreads();
    short8 af[4], bfv[4];
    #pragma unroll
    for (int i = 0; i < 4; ++i) af[i] = *(const short8*)&sm.Alds[(arow + i * 16) * 40 + aq];
    #pragma unroll
    for (int i = 0; i < 4; ++i) bfv[i] = *(const short8*)&sm.Blds[(wn * 4 + i) * 512 + lane * 8];
    #pragma unroll
    for (int i = 0; i < 4; ++i)
      #pragma unroll
      for (int jj = 0; jj < 4; ++jj)
        acc[i][jj] = __builtin_amdgcn_mfma_f32_16x16x32_bf16(af[i], bfv[jj], acc[i][jj], 0, 0, 0);
  }
  const int lcolbase = (bx % 3) * 128;
  float sums[4][4];
  #pragma unroll
  for (int i = 0; i < 4; ++i) {
    #pragma unroll
    for (int rr = 0; rr < 4; ++rr) {
      const int row = m0 + lrb + i * 16 + rr;
      const int cat = category[row];
      float s = 0.f;
      #pragma unroll
      for (int jj = 0; jj < 4; ++jj) {
        int cl = cb + jj * 16;
        float v = acc[i][jj][rr] + eb[bx * 128 + cl];
        v = fmaxf(v, 0.f);
        s = fmaf(v, hw[cat * HIDn + lcolbase + cl], s);
      }
      #pragma unroll
      for (int off = 8; off; off >>= 1) s += __shfl_xor(s, off);
      sums[i][rr] = s;
    }
  }
  __syncthreads();
  if ((lane & 15) == 0) {
    #pragma unroll
    for (int i = 0; i < 4; ++i)
      #pragma unroll
      for (int rr = 0; rr < 4; ++rr)
        sm.u.e.plds[wn][lrb + i * 16 + rr] = sums[i][rr];
  }
  __syncthreads();
  if (t < 128) partial[(size_t)bx * Bn + m0 + t] = sm.u.e.plds[0][t] + sm.u.e.plds[1][t];
}

// ====== K3: gate softmax + expert combine + head bias + sigmoid ============
__global__ __launch_bounds__(256) void final_kernel(
    const float* __restrict__ partial, const float* __restrict__ glogp,
    const float* __restrict__ gb2, const int* __restrict__ category,
    const float* __restrict__ hb, float* __restrict__ out) {
  const int row = blockIdx.x * 256 + threadIdx.x;
  const int cat = category[row];
  float gl[5];
  #pragma unroll
  for (int k = 0; k < 5; ++k)
    gl[k] = gb2[cat * 5 + k]
          + glogp[((size_t)0 * Bn + row) * 5 + k]
          + glogp[((size_t)1 * Bn + row) * 5 + k]
          + glogp[((size_t)2 * Bn + row) * 5 + k];
  float mx = fmaxf(fmaxf(fmaxf(gl[0], gl[1]), fmaxf(gl[2], gl[3])), gl[4]);
  float ek[5], es = 0.f;
  #pragma unroll
  for (int k = 0; k < 5; ++k) { ek[k] = __expf(gl[k] - mx); es += ek[k]; }
  const float einv = 1.f / es;
  float s = 0.f;
  #pragma unroll
  for (int k = 0; k < 5; ++k) {
    float ps = partial[(size_t)(3 * k) * Bn + row]
             + partial[(size_t)(3 * k + 1) * Bn + row]
             + partial[(size_t)(3 * k + 2) * Bn + row];
    s = fmaf(ek[k] * einv, ps, s);
  }
  s += hb[cat];
  out[row] = 1.f / (1.f + __expf(-s));
}

extern "C" void kernel_launch(void* const* d_in, const int* in_sizes, int n_in,
                              void* d_out, int out_size, void* d_ws, size_t ws_size,
                              hipStream_t stream) {
  const float* feature  = (const float*)d_in[0];
  const int*   masks    = (const int*)d_in[1];
  const int*   category = (const int*)d_in[2];
  const float* attn_w   = (const float*)d_in[3];
  // d_in[4] attn_b cancels in softmax
  const float* gate_w1  = (const float*)d_in[5];
  const float* gate_b1  = (const float*)d_in[6];
  const float* gate_w2  = (const float*)d_in[7];
  const float* gate_b2  = (const float*)d_in[8];
  const float* expert_w = (const float*)d_in[9];
  const float* expert_b = (const float*)d_in[10];
  const float* head_w   = (const float*)d_in[11];
  const float* head_b   = (const float*)d_in[12];
  float* out = (float*)d_out;

  char* ws = (char*)d_ws;
  unsigned short* pooled = (unsigned short*)(ws);             //  6,291,456 B
  unsigned short* Bpe    = (unsigned short*)(ws + 6291456);   //  2,949,120 B
  unsigned short* Bpg    = (unsigned short*)(ws + 9240576);   //  5,308,416 B
  int* rowsamp           = (int*)(ws + 14548992);             //     20,992 B
  int* meta              = (int*)(ws + 14569984);             //        512 B
  float* glogp           = (float*)(ws + 14570496);           //    245,760 B
  float* partial         = (float*)(ws + 14816256);           //    245,760 B

  prep_kernel<<<dim3(Bn + 2016 + 1), dim3(256), 0, stream>>>(
      feature, masks, attn_w, expert_w, gate_w1, category,
      pooled, Bpe, Bpg, rowsamp, meta);
  gemm_kernel<<<dim3(480 + 3 * MAXTILES), dim3(256), 0, stream>>>(
      pooled, Bpe, Bpg, expert_b, gate_b1, gate_w2, category, head_w,
      rowsamp, meta, partial, glogp);
  final_kernel<<<dim3(16), dim3(256), 0, stream>>>(
      partial, glogp, gate_b2, category, head_b, out);
}

// Round 9
// 179.766 us; speedup vs baseline: 4.5651x; 1.0233x over previous
//
#include <hip/hip_runtime.h>
#include <hip/hip_bf16.h>

#define Bn   4096
#define Sn   128
#define En   768
#define HIDn 384
#define NHn  9
#define NEn  5
#define MAXTILES 41       // max padded m-tiles: 32 + up to 8 from per-cat rounding

typedef __attribute__((ext_vector_type(8))) short short8;
typedef __attribute__((ext_vector_type(4))) float f32x4;

__device__ __forceinline__ unsigned short f2bf(float v) {
  unsigned int x = __float_as_uint(v);
  x += 0x7fffu + ((x >> 16) & 1u);   // RNE
  return (unsigned short)(x >> 16);
}
__device__ __forceinline__ float dot4v(f32x4 a, f32x4 b) {
  return fmaf(a.x, b.x, fmaf(a.y, b.y, fmaf(a.z, b.z, a.w * b.w)));
}
__device__ __forceinline__ f32x4 ntl(const f32x4* p) {
  return __builtin_nontemporal_load(p);   // streaming read, no L2 reuse
}

#if defined(__has_builtin) && __has_builtin(__builtin_amdgcn_global_load_lds)
#define HAVE_GLOAD_LDS 1
// async global->LDS: lane l reads 16B at g+l*8 ushorts, HW writes ldsbase+l*16B
__device__ __forceinline__ void gload16(const unsigned short* g, unsigned short* l) {
  __builtin_amdgcn_global_load_lds(
      (const __attribute__((address_space(1))) unsigned int*)g,
      (__attribute__((address_space(3))) unsigned int*)l, 16, 0, 0);
}
#else
#define HAVE_GLOAD_LDS 0
#endif

// process one feature row held in x0..x2 (12 floats/lane across 64 lanes)
#define PROC(x0, x1, x2) {                                                 \
    float part = dot4v(x0, aw0) + dot4v(x1, aw1) + dot4v(x2, aw2);         \
    _Pragma("unroll")                                                      \
    for (int off = 32; off; off >>= 1) part += __shfl_xor(part, off);      \
    float w = __expf(part);               /* |score| small: no max-sub */  \
    lsum += w;                                                             \
    p0 += w * (x0); p1 += w * (x1); p2 += w * (x2); }

// ====== K1: pool (blocks 0..4095) | pack (4096..6111) | sort (6112) =========
__global__ __launch_bounds__(256) void prep_kernel(
    const float* __restrict__ feature, const int* __restrict__ masks,
    const float* __restrict__ attn_w, const float* __restrict__ ew,
    const float* __restrict__ g1, const int* __restrict__ category,
    unsigned short* __restrict__ pooled, unsigned short* __restrict__ Bpe,
    unsigned short* __restrict__ Bpg, int* __restrict__ rowsamp,
    int* __restrict__ meta) {
  __shared__ __align__(16) union {
    struct { float pbuf[4][768]; float sbuf[4]; } pool;
    struct { int hist[NHn][256]; int padbase[NHn]; int total[NHn];
             int tilecat[MAXTILES]; int padTiles; } srt;
  } sm;
  const int t = threadIdx.x, lane = t & 63, wid = t >> 6;
  const int bid = blockIdx.x;

  if (bid < Bn) {                          // ---------------- pool ----------
    const int b = bid;
    const f32x4* aw = (const f32x4*)attn_w;
    const f32x4 aw0 = aw[lane], aw1 = aw[64 + lane], aw2 = aw[128 + lane];
    const f32x4* fb = (const f32x4*)(feature + (size_t)b * (Sn * En));
    unsigned long long bal = __ballot(lane < 32 && masks[b * Sn + wid * 32 + (lane & 31)] != 0);
    unsigned int m = (unsigned int)bal;
    const int rowbase = wid * 32;
    f32x4 p0 = {0,0,0,0}, p1 = {0,0,0,0}, p2 = {0,0,0,0};
    float lsum = 0.f;
    if (m) {                               // 2-deep software pipeline
      int s = __builtin_ctz(m); m &= m - 1;
      const f32x4* rp = fb + (rowbase + s) * 192;
      f32x4 a0 = ntl(rp + lane), a1 = ntl(rp + 64 + lane), a2 = ntl(rp + 128 + lane);
      if (m) {
        int s2 = __builtin_ctz(m); m &= m - 1;
        const f32x4* rq = fb + (rowbase + s2) * 192;
        f32x4 b0 = ntl(rq + lane), b1 = ntl(rq + 64 + lane), b2 = ntl(rq + 128 + lane);
        while (m) {
          int s3 = __builtin_ctz(m); m &= m - 1;
          const f32x4* rr = fb + (rowbase + s3) * 192;
          f32x4 n0 = ntl(rr + lane), n1 = ntl(rr + 64 + lane), n2 = ntl(rr + 128 + lane);
          PROC(a0, a1, a2);
          a0 = b0; a1 = b1; a2 = b2;
          b0 = n0; b1 = n1; b2 = n2;
        }
        PROC(a0, a1, a2);
        a0 = b0; a1 = b1; a2 = b2;
      }
      PROC(a0, a1, a2);
    }
    ((f32x4*)sm.pool.pbuf[wid])[lane] = p0;
    ((f32x4*)sm.pool.pbuf[wid])[64 + lane] = p1;
    ((f32x4*)sm.pool.pbuf[wid])[128 + lane] = p2;
    if (lane == 0) sm.pool.sbuf[wid] = lsum;
    __syncthreads();
    float total = sm.pool.sbuf[0] + sm.pool.sbuf[1] + sm.pool.sbuf[2] + sm.pool.sbuf[3];
    if (total == 0.f) {                    // all rows masked: uniform alpha
      p0 = p1 = p2 = f32x4{0,0,0,0};
      for (int s = 0; s < 32; ++s) {
        const f32x4* rp = fb + (rowbase + s) * 192;
        p0 += ntl(rp + lane); p1 += ntl(rp + 64 + lane); p2 += ntl(rp + 128 + lane);
      }
      ((f32x4*)sm.pool.pbuf[wid])[lane] = p0;
      ((f32x4*)sm.pool.pbuf[wid])[64 + lane] = p1;
      ((f32x4*)sm.pool.pbuf[wid])[128 + lane] = p2;
      __syncthreads();
      total = 128.f;
    }
    const float inv = 1.f / total;
    if (t < 192) {
      f32x4 s0 = ((const f32x4*)sm.pool.pbuf[0])[t];
      f32x4 s1 = ((const f32x4*)sm.pool.pbuf[1])[t];
      f32x4 s2 = ((const f32x4*)sm.pool.pbuf[2])[t];
      f32x4 s3 = ((const f32x4*)sm.pool.pbuf[3])[t];
      f32x4 smv = (s0 + s1) + (s2 + s3);
      ushort4 u4;
      u4.x = f2bf(smv.x * inv); u4.y = f2bf(smv.y * inv);
      u4.z = f2bf(smv.z * inv); u4.w = f2bf(smv.w * inv);
      ((ushort4*)pooled)[(size_t)b * 192 + t] = u4;
    }
    return;
  }

  if (bid < Bn + 2016) {                   // ---------------- pack ----------
    const int pair = (bid - Bn) * 4 + wid;
    const int q = lane >> 4, j = lane & 15;
    const float* src; unsigned short* dst; int kt;
    if (pair < 2880) {                     // expert: 120 ntiles x 24 kt
      int nt = pair / 24; kt = pair % 24;
      int col = nt * 16 + j;
      src = ew + (size_t)(col / HIDn) * (En * HIDn) + (col % HIDn);
      dst = Bpe + (size_t)pair * 512;
    } else {                               // gate: 9 heads x 24 ntiles x 24 kt
      int g = pair - 2880;
      int h = g / 576, rem = g % 576;
      int nt = rem / 24; kt = rem % 24;
      int col = nt * 16 + j;
      src = g1 + (size_t)h * (En * HIDn) + col;
      dst = Bpg + ((size_t)(h * 24 + nt) * 24 + kt) * 512;
    }
    unsigned short outv[8] __attribute__((aligned(16)));
    #pragma unroll
    for (int e = 0; e < 8; ++e) {
      int k = kt * 32 + q * 8 + e;
      outv[e] = f2bf(src[(size_t)k * HIDn]);
    }
    *(uint4*)&dst[lane * 8] = *(const uint4*)outv;
    return;
  }

  // -------- sort: stable counting sort by category, 128-padded tiles -------
  #pragma unroll
  for (int jj = 0; jj < NHn; ++jj) sm.srt.hist[jj][t] = 0;
  __syncthreads();
  for (int i = 0; i < 16; ++i) { int c = category[t * 16 + i]; sm.srt.hist[c][t]++; }
  __syncthreads();
  if (t < NHn) {
    int run = 0;
    for (int x = 0; x < 256; ++x) { int v = sm.srt.hist[t][x]; sm.srt.hist[t][x] = run; run += v; }
    sm.srt.total[t] = run;
  }
  __syncthreads();
  if (t == 0) {
    int pb = 0, mt = 0;
    for (int jj = 0; jj < NHn; ++jj) {
      sm.srt.padbase[jj] = pb;
      int tot = sm.srt.total[jj];
      int nt = (tot + 127) >> 7;
      for (int k2 = 0; k2 < nt; ++k2) {
        meta[1 + mt + k2] = jj;
        int vv = tot - (k2 << 7); if (vv > 128) vv = 128;
        meta[64 + mt + k2] = vv;
        sm.srt.tilecat[mt + k2] = jj;
      }
      mt += nt; pb += nt << 7;
    }
    meta[0] = mt; sm.srt.padTiles = mt;
  }
  __syncthreads();
  const int padM = sm.srt.padTiles << 7;
  for (int mm = t; mm < padM; mm += 256) {
    int h = sm.srt.tilecat[mm >> 7];
    if (mm - sm.srt.padbase[h] >= sm.srt.total[h]) rowsamp[mm] = 0;
  }
  for (int i = 0; i < 16; ++i) {           // stable scatter
    int idx = t * 16 + i; int c = category[idx];
    int off = sm.srt.hist[c][t]++;
    rowsamp[sm.srt.padbase[c] + off] = idx;
  }
}

// ====== K2: gemmg (blocks 0..122) | gemme (123..602) =======================
// BK=64 K-steps (12 iters, 24 barriers), B staged via global_load_lds
// (fragment-linear source/dest), A staged via VGPR into padded [128][72].
__global__ __launch_bounds__(256) void gemm_kernel(
    const unsigned short* __restrict__ pooled, const unsigned short* __restrict__ Bpe,
    const unsigned short* __restrict__ Bpg, const float* __restrict__ eb,
    const float* __restrict__ gb1, const float* __restrict__ g2,
    const int* __restrict__ category, const float* __restrict__ hw,
    const int* __restrict__ rowsamp, const int* __restrict__ meta,
    float* __restrict__ partial, float* __restrict__ glogp) {
  __shared__ __align__(16) struct {
    unsigned short Alds[128 * 72];         // 18,432 B (rows padded 64->72)
    unsigned short Blds[8 * 1024];         // 16,384 B (8 subtiles x 2 k-halves)
    union {
      struct { float plds[2][128]; } e;
      struct { int rs[128]; float w2[640]; } g;
    } u;
  } sm;
  const int t = threadIdx.x, lane = t & 63, wid = t >> 6;
  const int wm = wid >> 1, wn = wid & 1;
  const int bid = blockIdx.x;
  const int arow = wm * 64 + (lane & 15);
  const int aq = (lane >> 4) * 8;
  const int lrb = wm * 64 + ((lane >> 4) << 2);
  const int cb = wn * 64 + (lane & 15);
  const int srow = t >> 3, scol = (t & 7) * 8;   // A staging map
  f32x4 acc[4][4] = {};

  if (bid < 3 * MAXTILES) {                // -------------- gemmg ----------
    const int mt = bid / 3, bxg = bid % 3;
    if (mt >= meta[0]) return;
    const int h = meta[1 + mt], valid = meta[64 + mt];
    if (t < 128) sm.u.g.rs[t] = rowsamp[mt * 128 + t];
    const float* w2src = g2 + ((size_t)h * HIDn + bxg * 128) * 5;
    for (int idx = t; idx < 640; idx += 256) sm.u.g.w2[idx] = w2src[idx];
    __syncthreads();                       // rs ready for staging
    for (int kt2 = 0; kt2 < 12; ++kt2) {
      __syncthreads();
      #pragma unroll
      for (int i = 0; i < 4; ++i) {        // B: async frag-linear
        int chunk = wid * 4 + i, st = chunk >> 1, ks = chunk & 1;
#if HAVE_GLOAD_LDS
        gload16(&Bpg[(((size_t)h * 24 + bxg * 8 + st) * 24 + kt2 * 2 + ks) * 512 + lane * 8],
                &sm.Blds[st * 1024 + ks * 512]);
#else
        *(uint4*)&sm.Blds[st * 1024 + ks * 512 + lane * 8] =
            *(const uint4*)&Bpg[(((size_t)h * 24 + bxg * 8 + st) * 24 + kt2 * 2 + ks) * 512 + lane * 8];
#endif
      }
      #pragma unroll
      for (int rr = 0; rr < 4; ++rr) {     // A: gathered rows
        int row = srow + rr * 32;
        *(uint4*)&sm.Alds[row * 72 + scol] =
            *(const uint4*)&pooled[(size_t)sm.u.g.rs[row] * En + kt2 * 64 + scol];
      }
      __syncthreads();
      #pragma unroll
      for (int ks = 0; ks < 2; ++ks) {
        short8 af[4], bfv[4];
        #pragma unroll
        for (int i = 0; i < 4; ++i)
          af[i] = *(const short8*)&sm.Alds[(arow + i * 16) * 72 + ks * 32 + aq];
        #pragma unroll
        for (int j = 0; j < 4; ++j)
          bfv[j] = *(const short8*)&sm.Blds[(wn * 4 + j) * 1024 + ks * 512 + lane * 8];
        #pragma unroll
        for (int i = 0; i < 4; ++i)
          #pragma unroll
          for (int j = 0; j < 4; ++j)
            acc[i][j] = __builtin_amdgcn_mfma_f32_16x16x32_bf16(af[i], bfv[j], acc[i][j], 0, 0, 0);
      }
    }
    #pragma unroll
    for (int i = 0; i < 4; ++i) {
      #pragma unroll
      for (int rr = 0; rr < 4; ++rr) {
        const int lrow = lrb + i * 16 + rr;
        float s[5] = {0.f, 0.f, 0.f, 0.f, 0.f};
        #pragma unroll
        for (int jj = 0; jj < 4; ++jj) {
          int cl = cb + jj * 16;
          float v = acc[i][jj][rr] + gb1[h * HIDn + bxg * 128 + cl];
          v = fmaxf(v, 0.f);
          #pragma unroll
          for (int k = 0; k < 5; ++k) s[k] = fmaf(v, sm.u.g.w2[cl * 5 + k], s[k]);
        }
        #pragma unroll
        for (int k = 0; k < 5; ++k)
          #pragma unroll
          for (int off = 8; off; off >>= 1) s[k] += __shfl_xor(s[k], off);
        if ((lane & 15) == 0 && lrow < valid) {
          int samp = sm.u.g.rs[lrow];
          #pragma unroll
          for (int k = 0; k < 5; ++k)
            glogp[((size_t)bxg * Bn + samp) * 5 + k] = s[k];
        }
      }
    }
    return;
  }

  // ---------------- gemme ----------
  const int e = bid - 3 * MAXTILES;
  const int bx = e % 15, by = e / 15;
  const int m0 = by * 128, ntg0 = bx * 8;
  for (int kt2 = 0; kt2 < 12; ++kt2) {
    __syncthreads();
    #pragma unroll
    for (int i = 0; i < 4; ++i) {          // B: async frag-linear
      int chunk = wid * 4 + i, st = chunk >> 1, ks = chunk & 1;
#if HAVE_GLOAD_LDS
      gload16(&Bpe[((size_t)(ntg0 + st) * 24 + kt2 * 2 + ks) * 512 + lane * 8],
              &sm.Blds[st * 1024 + ks * 512]);
#else
      *(uint4*)&sm.Blds[st * 1024 + ks * 512 + lane * 8] =
          *(const uint4*)&Bpe[((size_t)(ntg0 + st) * 24 + kt2 * 2 + ks) * 512 + lane * 8];
#endif
    }
    #pragma unroll
    for (int rr = 0; rr < 4; ++rr) {       // A: contiguous rows
      int row = srow + rr * 32;
      *(uint4*)&sm.Alds[row * 72 + scol] =
          *(const uint4*)&pooled[(size_t)(m0 + row) * En + kt2 * 64 + scol];
    }
    __syncthreads();
    #pragma unroll
    for (int ks = 0; ks < 2; ++ks) {
      short8 af[4], bfv[4];
      #pragma unroll
      for (int i = 0; i < 4; ++i)
        af[i] = *(const short8*)&sm.Alds[(arow + i * 16) * 72 + ks * 32 + aq];
      #pragma unroll
      for (int j = 0; j < 4; ++j)
        bfv[j] = *(const short8*)&sm.Blds[(wn * 4 + j) * 1024 + ks * 512 + lane * 8];
      #pragma unroll
      for (int i = 0; i < 4; ++i)
        #pragma unroll
        for (int j = 0; j < 4; ++j)
          acc[i][j] = __builtin_amdgcn_mfma_f32_16x16x32_bf16(af[i], bfv[j], acc[i][j], 0, 0, 0);
    }
  }
  const int lcolbase = (bx % 3) * 128;
  float sums[4][4];
  #pragma unroll
  for (int i = 0; i < 4; ++i) {
    #pragma unroll
    for (int rr = 0; rr < 4; ++rr) {
      const int row = m0 + lrb + i * 16 + rr;
      const int cat = category[row];
      float s = 0.f;
      #pragma unroll
      for (int jj = 0; jj < 4; ++jj) {
        int cl = cb + jj * 16;
        float v = acc[i][jj][rr] + eb[bx * 128 + cl];
        v = fmaxf(v, 0.f);
        s = fmaf(v, hw[cat * HIDn + lcolbase + cl], s);
      }
      #pragma unroll
      for (int off = 8; off; off >>= 1) s += __shfl_xor(s, off);
      sums[i][rr] = s;
    }
  }
  __syncthreads();
  if ((lane & 15) == 0) {
    #pragma unroll
    for (int i = 0; i < 4; ++i)
      #pragma unroll
      for (int rr = 0; rr < 4; ++rr)
        sm.u.e.plds[wn][lrb + i * 16 + rr] = sums[i][rr];
  }
  __syncthreads();
  if (t < 128) partial[(size_t)bx * Bn + m0 + t] = sm.u.e.plds[0][t] + sm.u.e.plds[1][t];
}

// ====== K3: gate softmax + expert combine + head bias + sigmoid ============
__global__ __launch_bounds__(256) void final_kernel(
    const float* __restrict__ partial, const float* __restrict__ glogp,
    const float* __restrict__ gb2, const int* __restrict__ category,
    const float* __restrict__ hb, float* __restrict__ out) {
  const int row = blockIdx.x * 256 + threadIdx.x;
  const int cat = category[row];
  float gl[5];
  #pragma unroll
  for (int k = 0; k < 5; ++k)
    gl[k] = gb2[cat * 5 + k]
          + glogp[((size_t)0 * Bn + row) * 5 + k]
          + glogp[((size_t)1 * Bn + row) * 5 + k]
          + glogp[((size_t)2 * Bn + row) * 5 + k];
  float mx = fmaxf(fmaxf(fmaxf(gl[0], gl[1]), fmaxf(gl[2], gl[3])), gl[4]);
  float ek[5], es = 0.f;
  #pragma unroll
  for (int k = 0; k < 5; ++k) { ek[k] = __expf(gl[k] - mx); es += ek[k]; }
  const float einv = 1.f / es;
  float s = 0.f;
  #pragma unroll
  for (int k = 0; k < 5; ++k) {
    float ps = partial[(size_t)(3 * k) * Bn + row]
             + partial[(size_t)(3 * k + 1) * Bn + row]
             + partial[(size_t)(3 * k + 2) * Bn + row];
    s = fmaf(ek[k] * einv, ps, s);
  }
  s += hb[cat];
  out[row] = 1.f / (1.f + __expf(-s));
}

extern "C" void kernel_launch(void* const* d_in, const int* in_sizes, int n_in,
                              void* d_out, int out_size, void* d_ws, size_t ws_size,
                              hipStream_t stream) {
  const float* feature  = (const float*)d_in[0];
  const int*   masks    = (const int*)d_in[1];
  const int*   category = (const int*)d_in[2];
  const float* attn_w   = (const float*)d_in[3];
  // d_in[4] attn_b cancels in softmax
  const float* gate_w1  = (const float*)d_in[5];
  const float* gate_b1  = (const float*)d_in[6];
  const float* gate_w2  = (const float*)d_in[7];
  const float* gate_b2  = (const float*)d_in[8];
  const float* expert_w = (const float*)d_in[9];
  const float* expert_b = (const float*)d_in[10];
  const float* head_w   = (const float*)d_in[11];
  const float* head_b   = (const float*)d_in[12];
  float* out = (float*)d_out;

  char* ws = (char*)d_ws;
  unsigned short* pooled = (unsigned short*)(ws);             //  6,291,456 B
  unsigned short* Bpe    = (unsigned short*)(ws + 6291456);   //  2,949,120 B
  unsigned short* Bpg    = (unsigned short*)(ws + 9240576);   //  5,308,416 B
  int* rowsamp           = (int*)(ws + 14548992);             //     20,992 B
  int* meta              = (int*)(ws + 14569984);             //        512 B
  float* glogp           = (float*)(ws + 14570496);           //    245,760 B
  float* partial         = (float*)(ws + 14816256);           //    245,760 B

  prep_kernel<<<dim3(Bn + 2016 + 1), dim3(256), 0, stream>>>(
      feature, masks, attn_w, expert_w, gate_w1, category,
      pooled, Bpe, Bpg, rowsamp, meta);
  gemm_kernel<<<dim3(480 + 3 * MAXTILES), dim3(256), 0, stream>>>(
      pooled, Bpe, Bpg, expert_b, gate_b1, gate_w2, category, head_w,
      rowsamp, meta, partial, glogp);
  final_kernel<<<dim3(16), dim3(256), 0, stream>>>(
      partial, glogp, gate_b2, category, head_b, out);
}